// Round 4
// baseline (3371.617 us; speedup 1.0000x reference)
//
#include <hip/hip_runtime.h>

#define BB 32
#define NN 1024
#define HH 512
#define NS 1023   // S length per row

// ---------------------------------------------------------------- kernel 1
// per-row L2 norm of seg: nrm[row] = sqrt(sum_j seg[row][j]^2)
__global__ __launch_bounds__(64) void k_rnorm(const float* __restrict__ seg,
                                              float* __restrict__ nrm) {
  int row = blockIdx.x;            // 0 .. B*N-1
  int lane = threadIdx.x;          // 0..63, 8 elems each
  const float4* p = (const float4*)(seg + ((size_t)row << 9) + lane * 8);
  float4 a = p[0], b = p[1];
  float s = a.x * a.x + a.y * a.y + a.z * a.z + a.w * a.w +
            b.x * b.x + b.y * b.y + b.z * b.z + b.w * b.w;
#pragma unroll
  for (int m = 32; m; m >>= 1) s += __shfl_xor(s, m, 64);
  if (lane == 0) nrm[row] = sqrtf(s);
}

// ---------------------------------------------------------------- kernel 2
// S[b][n] = relu([seg[n]/nrm[n], seg[n+1]/nrm[n+1]] @ W1 + b1) @ W2
// block: 256 thr, tile 16 S-rows x 512 hidden cols, K=1024.
__global__ __launch_bounds__(256) void k_sgemm(const float* __restrict__ seg,
                                               const float* __restrict__ nrm,
                                               const float* __restrict__ W1,
                                               const float* __restrict__ b1,
                                               const float* __restrict__ W2,
                                               float* __restrict__ S) {
  __shared__ float Al[512 * 20];   // [j][r], r=0..16, stride 20 (16B-aligned rows of 4)
  __shared__ float Wl[16 * 256];   // K-chunk 16 x 256 cols
  __shared__ float b1s[512];
  __shared__ float W2s[512];

  int b   = blockIdx.y;
  int n0  = blockIdx.x * 16;
  int tid = threadIdx.x;
  for (int i = tid; i < 512; i += 256) { b1s[i] = b1[i]; W2s[i] = W2[i]; }
  for (int idx = tid; idx < 17 * 512; idx += 256) {
    int r = idx >> 9, j = idx & 511;
    int row = n0 + r; if (row > NN - 1) row = NN - 1;
    size_t g = ((size_t)b << 10) + row;
    Al[j * 20 + r] = seg[g * HH + j] / nrm[g];   // fp32 normalize, matches ref
  }
  int lane = tid & 63;
  int g    = tid >> 6;
  int r0   = g * 4;          // rows r0..r0+3 (wave-uniform)
  int c0   = lane * 4;       // cols within 256-chunk

  float sacc[4] = {0.f, 0.f, 0.f, 0.f};
  for (int kc = 0; kc < 2; ++kc) {
    float acc[4][4];
#pragma unroll
    for (int i = 0; i < 4; ++i)
#pragma unroll
      for (int l = 0; l < 4; ++l) acc[i][l] = 0.f;

    for (int jb = 0; jb < 1024; jb += 16) {
      __syncthreads();
      for (int idx = tid; idx < 16 * 256; idx += 256) {
        int rr = idx >> 8, cc = idx & 255;
        Wl[rr * 256 + cc] = W1[(size_t)(jb + rr) * HH + kc * 256 + cc];
      }
      __syncthreads();
      if (jb < 512) {
#pragma unroll
        for (int jj = 0; jj < 16; ++jj) {
          const float4 a = *(const float4*)&Al[(jb + jj) * 20 + r0];
          const float4 w = *(const float4*)&Wl[jj * 256 + c0];
          float av[4] = {a.x, a.y, a.z, a.w};
          float wv[4] = {w.x, w.y, w.z, w.w};
#pragma unroll
          for (int i = 0; i < 4; ++i)
#pragma unroll
            for (int l = 0; l < 4; ++l) acc[i][l] = fmaf(av[i], wv[l], acc[i][l]);
        }
      } else {
#pragma unroll
        for (int jj = 0; jj < 16; ++jj) {
          int j = jb + jj - 512;
          float av[4];
#pragma unroll
          for (int i = 0; i < 4; ++i) av[i] = Al[j * 20 + r0 + 1 + i];  // seg row n+1
          const float4 w = *(const float4*)&Wl[jj * 256 + c0];
          float wv[4] = {w.x, w.y, w.z, w.w};
#pragma unroll
          for (int i = 0; i < 4; ++i)
#pragma unroll
            for (int l = 0; l < 4; ++l) acc[i][l] = fmaf(av[i], wv[l], acc[i][l]);
        }
      }
    }
    // fold this 256-col chunk: relu(acc + b1) . W2
#pragma unroll
    for (int i = 0; i < 4; ++i) {
#pragma unroll
      for (int l = 0; l < 4; ++l) {
        int col = kc * 256 + c0 + l;
        float h = acc[i][l] + b1s[col];
        h = h > 0.f ? h : 0.f;
        sacc[i] = fmaf(h, W2s[col], sacc[i]);
      }
    }
  }
  // reduce across the 64 lanes of the wave (each wave owns 4 S-rows)
#pragma unroll
  for (int i = 0; i < 4; ++i) {
    float v = sacc[i];
#pragma unroll
    for (int m = 32; m; m >>= 1) v += __shfl_xor(v, m, 64);
    if (lane == 0) {
      int n = n0 + r0 + i;
      if (n < NS) S[((size_t)b << 10) + n] = v;
    }
  }
}

// ---------------------------------------------------------------- kernel 3
// per batch row: D, peak detect, straight-through boundaries, sequential
// cumsum, segment assignment (sparse Wseg), per-segment totals and n-ranges.
__global__ __launch_bounds__(256) void k_row(const float* __restrict__ S,
                                             const float* __restrict__ mask,
                                             int* __restrict__ assign,
                                             float* __restrict__ weight,
                                             float* __restrict__ total,
                                             int* __restrict__ startn,
                                             int* __restrict__ endn) {
  int b = blockIdx.x, tid = threadIdx.x;
  __shared__ float Ssh[NS];
  __shared__ float Dsh[NS];
  __shared__ float tsh[NN];
  __shared__ float bsh[NN];
  __shared__ float totl[NN];
  __shared__ int   stl[NN];
  __shared__ int   enl[NN];
  __shared__ float red[256];

  for (int n = tid; n < NS; n += 256) Ssh[n] = S[((size_t)b << 10) + n];
  __syncthreads();

  float mn = INFINITY, mx = -INFINITY;
  for (int n = tid; n < NS; n += 256) {
    float v = Ssh[n];
    mn = fminf(mn, v); mx = fmaxf(mx, v);
  }
  red[tid] = mn; __syncthreads();
  for (int s = 128; s; s >>= 1) { if (tid < s) red[tid] = fminf(red[tid], red[tid + s]); __syncthreads(); }
  float Smin = red[0]; __syncthreads();
  red[tid] = mx; __syncthreads();
  for (int s = 128; s; s >>= 1) { if (tid < s) red[tid] = fmaxf(red[tid], red[tid + s]); __syncthreads(); }
  float Smax = red[0]; __syncthreads();

  for (int n = tid; n < NS; n += 256)
    Dsh[n] = 1.0f - (Ssh[n] - Smin) / (Smax - Smin);
  __syncthreads();

  for (int n = tid; n < NN; n += 256) {
    float P;
    if (n >= NS) {
      P = 0.f;                         // padded column
    } else {
      float D = Dsh[n];
      float fo, so;
      if (n == 0)            fo = fmaxf(D - Dsh[1], 0.f);
      else if (n >= NS - 2)  fo = fmaxf(D - Dsh[n - 2], 0.f);      // ref's final overwrite of cols -2:
      else                   fo = fminf(fmaxf(D - Dsh[n - 1], 0.f),
                                        fmaxf(D - Dsh[n + 1], 0.f));
      if (n <= 1)            so = fmaxf(D - Dsh[n + 2], 0.f);
      else if (n >= NS - 2)  so = 0.f;
      else                   so = fminf(fmaxf(D - Dsh[n - 2], 0.f),
                                        fmaxf(D - Dsh[n + 2], 0.f));
      P = fminf(fmaxf(fmaxf(fo, so) - 0.05f, 0.f), fo);
    }
    float m = mask[((size_t)b << 10) + n];
    P = P + (m - 1.0f);
    P = P > 0.f ? P : 0.f;
    float bs = tanhf(10.0f * P);
    float bh = tanhf(100000.0f * P);
    tsh[n] = bs + (bh - bs);           // replicate straight-through arithmetic exactly
  }
  __syncthreads();

  if (tid == 0) {                      // numpy-order sequential cumsum
    float acc = 0.f;
    for (int n = 0; n < NN; n += 8) {
      float t0 = tsh[n + 0], t1 = tsh[n + 1], t2 = tsh[n + 2], t3 = tsh[n + 3];
      float t4 = tsh[n + 4], t5 = tsh[n + 5], t6 = tsh[n + 6], t7 = tsh[n + 7];
      acc += t0; bsh[n + 0] = acc; acc += t1; bsh[n + 1] = acc;
      acc += t2; bsh[n + 2] = acc; acc += t3; bsh[n + 3] = acc;
      acc += t4; bsh[n + 4] = acc; acc += t5; bsh[n + 5] = acc;
      acc += t6; bsh[n + 6] = acc; acc += t7; bsh[n + 7] = acc;
    }
  }
  __syncthreads();

  float add1 = (bsh[0] == 0.0f) ? 1.0f : 0.0f;
  int   num  = (int)(bsh[NN - 1] + add1) + 1;

  for (int mi = tid; mi < NN; mi += 256) { totl[mi] = 0.f; stl[mi] = 1 << 30; enl[mi] = -1; }
  __syncthreads();

  for (int n = tid; n < NN; n += 256) {
    float bv = bsh[n] + add1;
    float kf = rintf(bv);
    int   k  = (int)kf;
    int   a  = -1; float w = 0.f;
    if (k >= 1 && k <= num && k <= NN) {
      float v = fabsf(kf - bv);
      w = 1.0f - tanhf(100000.0f * v);   // matches Wseg entry; ==0 when tanhf saturates
      if (w > 0.f) {
        a = k - 1;
        atomicAdd(&totl[a], w);
        atomicMin(&stl[a], n);
        atomicMax(&enl[a], n);
      } else {
        a = -1; w = 0.f;
      }
    }
    assign[((size_t)b << 10) + n] = a;
    weight[((size_t)b << 10) + n] = w;
  }
  __syncthreads();
  for (int mi = tid; mi < NN; mi += 256) {
    total [((size_t)b << 10) + mi] = totl[mi];
    startn[((size_t)b << 10) + mi] = stl[mi];
    endn  [((size_t)b << 10) + mi] = enl[mi];
  }
}

// ---------------------------------------------------------------- kernel 4
// word_rep[b][m][:] = sum_n (w[n]/total[m]) * seg[b][n][:], f32 into d_out
__global__ __launch_bounds__(64) void k_pool(const float* __restrict__ seg,
                                             const int* __restrict__ assign,
                                             const float* __restrict__ weight,
                                             const float* __restrict__ total,
                                             const int* __restrict__ startn,
                                             const int* __restrict__ endn,
                                             float* __restrict__ wrep) {
  int bm = blockIdx.x;                // b*1024 + m
  int b  = bm >> 10, m = bm & 1023;
  int lane = threadIdx.x;
  float acc[8] = {0.f, 0.f, 0.f, 0.f, 0.f, 0.f, 0.f, 0.f};
  float tm = total[bm];
  if (tm > 0.f) {
    int s = startn[bm], e = endn[bm];
    for (int n = s; n <= e; ++n) {
      if (assign[((size_t)b << 10) + n] != m) continue;
      float coef = weight[((size_t)b << 10) + n] / tm;
      const float4* p = (const float4*)(seg + (((size_t)b << 10) + n) * HH + lane * 8);
      float4 x = p[0], y = p[1];
      acc[0] = fmaf(coef, x.x, acc[0]); acc[1] = fmaf(coef, x.y, acc[1]);
      acc[2] = fmaf(coef, x.z, acc[2]); acc[3] = fmaf(coef, x.w, acc[3]);
      acc[4] = fmaf(coef, y.x, acc[4]); acc[5] = fmaf(coef, y.y, acc[5]);
      acc[6] = fmaf(coef, y.z, acc[6]); acc[7] = fmaf(coef, y.w, acc[7]);
    }
  }
  float4* dst = (float4*)(wrep + (size_t)bm * HH + lane * 8);
  dst[0] = make_float4(acc[0], acc[1], acc[2], acc[3]);
  dst[1] = make_float4(acc[4], acc[5], acc[6], acc[7]);
}

// ---------------------------------------------------------------- kernel 5
// out = (relu(wrep @ We1 + be1) @ We2 + be2) * (wrep != 0), in-place on d_out.
// block: 256 thr, tile 16 rows x 512 cols, K=512 twice. Rows block-exclusive,
// elements thread-exclusive (read-before-write) -> in-place safe.
__global__ __launch_bounds__(256) void k_out(const float* __restrict__ We1,
                                             const float* __restrict__ be1,
                                             const float* __restrict__ We2,
                                             const float* __restrict__ be2,
                                             float* __restrict__ io) {
  __shared__ float Al[512 * 20];   // transposed A / hidden tile [j][r], r=0..15
  __shared__ float Wl[8 * 512];    // K-chunk 8 x 512
  __shared__ float bias1[512];
  __shared__ float bias2[512];

  int row0 = blockIdx.x * 16;      // global row in [0, 32768)
  int tid  = threadIdx.x;
  for (int i = tid; i < 512; i += 256) { bias1[i] = be1[i]; bias2[i] = be2[i]; }
  for (int idx = tid; idx < 16 * 512; idx += 256) {
    int r = idx >> 9, j = idx & 511;
    Al[j * 20 + r] = io[(size_t)(row0 + r) * HH + j];
  }
  int lane = tid & 63;
  int g    = tid >> 6;
  int r0   = g * 4;
  int c0   = lane * 8;

  float acc[4][8];
  // ---- GEMM1: hidden = relu(wrep @ We1 + be1)
#pragma unroll
  for (int i = 0; i < 4; ++i)
#pragma unroll
    for (int l = 0; l < 8; ++l) acc[i][l] = 0.f;
  for (int jb = 0; jb < 512; jb += 8) {
    __syncthreads();
    for (int idx = tid; idx < 8 * 512; idx += 256) {
      int rr = idx >> 9, cc = idx & 511;
      Wl[rr * 512 + cc] = We1[(size_t)(jb + rr) * HH + cc];
    }
    __syncthreads();
#pragma unroll
    for (int jj = 0; jj < 8; ++jj) {
      const float4 a  = *(const float4*)&Al[(jb + jj) * 20 + r0];
      const float4 w0 = *(const float4*)&Wl[jj * 512 + c0];
      const float4 w1 = *(const float4*)&Wl[jj * 512 + c0 + 4];
      float av[4] = {a.x, a.y, a.z, a.w};
      float wv[8] = {w0.x, w0.y, w0.z, w0.w, w1.x, w1.y, w1.z, w1.w};
#pragma unroll
      for (int i = 0; i < 4; ++i)
#pragma unroll
        for (int l = 0; l < 8; ++l) acc[i][l] = fmaf(av[i], wv[l], acc[i][l]);
    }
  }
  __syncthreads();
  // write hidden (transposed) back into Al
#pragma unroll
  for (int i = 0; i < 4; ++i)
#pragma unroll
    for (int l = 0; l < 8; ++l) {
      int col = c0 + l;
      float h = acc[i][l] + bias1[col];
      h = h > 0.f ? h : 0.f;
      Al[col * 20 + r0 + i] = h;
    }
  // ---- GEMM2: out = hidden @ We2 + be2
#pragma unroll
  for (int i = 0; i < 4; ++i)
#pragma unroll
    for (int l = 0; l < 8; ++l) acc[i][l] = 0.f;
  for (int jb = 0; jb < 512; jb += 8) {
    __syncthreads();
    for (int idx = tid; idx < 8 * 512; idx += 256) {
      int rr = idx >> 9, cc = idx & 511;
      Wl[rr * 512 + cc] = We2[(size_t)(jb + rr) * HH + cc];
    }
    __syncthreads();
#pragma unroll
    for (int jj = 0; jj < 8; ++jj) {
      const float4 a  = *(const float4*)&Al[(jb + jj) * 20 + r0];
      const float4 w0 = *(const float4*)&Wl[jj * 512 + c0];
      const float4 w1 = *(const float4*)&Wl[jj * 512 + c0 + 4];
      float av[4] = {a.x, a.y, a.z, a.w};
      float wv[8] = {w0.x, w0.y, w0.z, w0.w, w1.x, w1.y, w1.z, w1.w};
#pragma unroll
      for (int i = 0; i < 4; ++i)
#pragma unroll
        for (int l = 0; l < 8; ++l) acc[i][l] = fmaf(av[i], wv[l], acc[i][l]);
    }
  }
  // epilogue: bias, elementwise mask (wrep == 0), f32 store in place
#pragma unroll
  for (int i = 0; i < 4; ++i) {
    size_t rowi = (size_t)(row0 + r0 + i);
#pragma unroll
    for (int l = 0; l < 8; ++l) {
      int col = c0 + l;
      float o = acc[i][l] + bias2[col];
      float wr = io[rowi * HH + col];
      if (wr == 0.f) o = 0.f;           // +-0 both match ref's (word_rep == 0)
      io[rowi * HH + col] = o;
    }
  }
}

// ---------------------------------------------------------------- kernel 6
// Diagnostic tripwire: if pipeline state is unhealthy, encode stage flags
// into out[0] as float32 (visible to validation). Healthy -> no-op.
__global__ void k_diag(const float* __restrict__ nrm,
                       const float* __restrict__ S,
                       const float* __restrict__ total,
                       float* __restrict__ out, int hostcode) {
  if (hostcode != 0) { out[0] = (float)hostcode; return; }
  float n0 = nrm[0];
  bool f_nrm = (n0 == n0) && n0 > 0.f && n0 < 1e30f;
  float s0 = S[0], s1 = S[1], s2 = S[2], s3 = S[3];
  bool f_sg = (s0 == s0) && fabsf(s0) < 1e30f && !(s0 == s1 && s1 == s2 && s2 == s3);
  float t0 = total[0];
  bool f_row = (t0 == t0) && t0 >= 0.f;
  float ts = 0.f;
  for (int m = 0; m < 1024; ++m) ts += total[m];
  bool f_tot = (ts == ts) && ts > 0.f;
  bool f_pool = false;
  for (int j = 0; j < 512; ++j)
    if (out[j] != 0.f) { f_pool = true; break; }
  if (f_nrm && f_sg && f_row && f_tot && f_pool) return;  // healthy: keep output
  int msk = (f_nrm ? 32 : 0) | (f_sg ? 16 : 0) | (f_row ? 8 : 0) |
            (f_tot ? 4 : 0) | (f_pool ? 2 : 0) | 1;
  out[0] = 256.0f * (float)msk;
}

// ---------------------------------------------------------------- launch
extern "C" void kernel_launch(void* const* d_in, const int* in_sizes, int n_in,
                              void* d_out, int out_size, void* d_ws, size_t ws_size,
                              hipStream_t stream) {
  const float* seg  = (const float*)d_in[0];
  const float* mask = (const float*)d_in[1];
  const float* W1   = (const float*)d_in[2];
  const float* b1   = (const float*)d_in[3];
  const float* W2   = (const float*)d_in[4];
  const float* We1  = (const float*)d_in[5];
  const float* be1  = (const float*)d_in[6];
  const float* We2  = (const float*)d_in[7];
  const float* be2  = (const float*)d_in[8];

  const size_t NROW = (size_t)BB * NN;            // 32768
  float* ws = (float*)d_ws;
  float* nrm    = ws;
  float* S      = nrm + NROW;
  int*   assign = (int*)(S + NROW);
  float* weight = (float*)(assign + NROW);
  float* total  = weight + NROW;
  int*   startn = (int*)(total + NROW);
  int*   endn   = startn + NROW;                  // total ws: 7*128KB = 896KB

  float* out = (float*)d_out;                     // f32; also the wrep buffer

  int hostcode = 0;
  bool sizes_ok = (n_in == 9) &&
    in_sizes[0] == 16777216 && in_sizes[1] == 32768 &&
    in_sizes[2] == 524288  && in_sizes[3] == 512 && in_sizes[4] == 512 &&
    in_sizes[5] == 262144  && in_sizes[6] == 512 &&
    in_sizes[7] == 262144  && in_sizes[8] == 512;
  if (!sizes_ok) hostcode += 16384;
  if (ws_size < (size_t)7 * NROW * 4) hostcode += 32768;
  if (out_size != 16777216) hostcode += 8192;

  k_rnorm<<<dim3(BB * NN), dim3(64), 0, stream>>>(seg, nrm);
  k_sgemm<<<dim3(64, BB),  dim3(256), 0, stream>>>(seg, nrm, W1, b1, W2, S);
  k_row  <<<dim3(BB),      dim3(256), 0, stream>>>(S, mask, assign, weight, total, startn, endn);
  k_pool <<<dim3(BB * NN), dim3(64), 0, stream>>>(seg, assign, weight, total, startn, endn, out);
  k_out  <<<dim3((BB * NN) / 16), dim3(256), 0, stream>>>(We1, be1, We2, be2, out);
  k_diag <<<dim3(1), dim3(1), 0, stream>>>(nrm, S, total, out, hostcode);
}

// Round 5
// 401.901 us; speedup vs baseline: 8.3892x; 8.3892x over previous
//
#include <hip/hip_runtime.h>

#define BB 32
#define NN 1024
#define HH 512
#define NS 1023   // S length per row

typedef unsigned short u16;
typedef unsigned int   u32;
typedef __attribute__((ext_vector_type(8))) short bf16x8;
typedef __attribute__((ext_vector_type(4))) float f32x4;

__device__ __forceinline__ float bf2f(u16 h) {
  union { u32 u; float f; } c; c.u = ((u32)h) << 16; return c.f;
}
__device__ __forceinline__ u16 f2bf(float f) {
  union { float f; u32 u; } c; c.f = f;
  u32 u = c.u;
  return (u16)((u + 0x7fffu + ((u >> 16) & 1u)) >> 16);
}
// split x = hi + lo (each bf16); residual ~2^-18 relative
__device__ __forceinline__ void split_bf(float x, u16& hi, u16& lo) {
  hi = f2bf(x);
  lo = f2bf(x - bf2f(hi));
}

// ---------------------------------------------------------------- prep A
// normalize seg rows, split to bf16 hi/lo planes stored in d_out:
//   ahi = (u16*)d_out, alo = ahi + 32768*512
__global__ __launch_bounds__(64) void k_prep_a(const float* __restrict__ seg,
                                               u16* __restrict__ ahi,
                                               u16* __restrict__ alo) {
  int row = blockIdx.x, lane = threadIdx.x;
  const float4* p = (const float4*)(seg + ((size_t)row << 9) + lane * 8);
  float4 a = p[0], b = p[1];
  float v[8] = {a.x, a.y, a.z, a.w, b.x, b.y, b.z, b.w};
  float s = 0.f;
#pragma unroll
  for (int i = 0; i < 8; ++i) s += v[i] * v[i];
#pragma unroll
  for (int m = 32; m; m >>= 1) s += __shfl_xor(s, m, 64);
  float nrm = sqrtf(s);
  u16 h[8], l[8];
#pragma unroll
  for (int i = 0; i < 8; ++i) split_bf(v[i] / nrm, h[i], l[i]);
  size_t off = ((size_t)row << 9) + lane * 8;
  *(uint4*)(ahi + off) = make_uint4(h[0] | (h[1] << 16), h[2] | (h[3] << 16),
                                    h[4] | (h[5] << 16), h[6] | (h[7] << 16));
  *(uint4*)(alo + off) = make_uint4(l[0] | (l[1] << 16), l[2] | (l[3] << 16),
                                    l[4] | (l[5] << 16), l[6] | (l[7] << 16));
}

// ---------------------------------------------------------------- prep W
// W1(1024x512) -> transposed hi/lo bf16 planes [n=512][k=1024];
// We1,We2(512x512) -> transposed single bf16 [n=512][k=512]; zero S.
__global__ __launch_bounds__(256) void k_prep_w(const float* __restrict__ W1,
                                                const float* __restrict__ We1,
                                                const float* __restrict__ We2,
                                                u16* __restrict__ w1h,
                                                u16* __restrict__ w1l,
                                                u16* __restrict__ we1t,
                                                u16* __restrict__ we2t,
                                                float* __restrict__ S) {
  int n = blockIdx.x, t = threadIdx.x;
#pragma unroll
  for (int kk = 0; kk < 4; ++kk) {
    int k = t * 4 + kk;                       // 0..1023
    u16 hi, lo; split_bf(W1[(size_t)k * HH + n], hi, lo);
    w1h[(size_t)n * 1024 + k] = hi;
    w1l[(size_t)n * 1024 + k] = lo;
  }
#pragma unroll
  for (int kk = 0; kk < 2; ++kk) {
    int k = t * 2 + kk;                       // 0..511
    we1t[(size_t)n * HH + k] = f2bf(We1[(size_t)k * HH + n]);
    we2t[(size_t)n * HH + k] = f2bf(We2[(size_t)k * HH + n]);
  }
  if (n < 128) S[n * 256 + t] = 0.f;          // zero 32768-entry S
}

// ---------------------------------------------------------------- S-GEMM (MFMA)
// hidden = relu(cat(A[n],A[n+1]) @ W1 + b1); S[n] += hidden_chunk . W2_chunk
// block tile: 64 S-rows x 128 hidden cols, K=1024 (concat). 3-pass split bf16.
// grid (4 nblk, 16 mblk, 32 b), 256 thr = 4 waves, each wave 32m x 64n.
__global__ __launch_bounds__(256) void k_sgemm(const u16* __restrict__ ahi,
                                               const u16* __restrict__ alo,
                                               const u16* __restrict__ w1h,
                                               const u16* __restrict__ w1l,
                                               const float* __restrict__ b1,
                                               const float* __restrict__ W2,
                                               float* __restrict__ S) {
  __shared__ u16 Ah[64 * 40], Al_[64 * 40];   // [m][k] stride 40 (pad 8)
  __shared__ u16 Wh[128 * 40], Wl[128 * 40];  // [n][k] stride 40

  int tid = threadIdx.x;
  int wave = tid >> 6, lane = tid & 63, quad = lane >> 4, l15 = lane & 15;
  int wm = wave >> 1, wn = wave & 1;
  int b = blockIdx.z, mblk = blockIdx.y, nblk = blockIdx.x;
  int rowbase = b * NN + mblk * 64;           // global A row for m=0, half 0
  int ncol0 = nblk * 128;                     // hidden col base

  f32x4 acc[2][4];
#pragma unroll
  for (int mi = 0; mi < 2; ++mi)
#pragma unroll
    for (int ni = 0; ni < 4; ++ni) acc[mi][ni] = (f32x4){0.f, 0.f, 0.f, 0.f};

  for (int ks = 0; ks < 32; ++ks) {
    int k0 = ks * 32, half = k0 >> 9, cb = k0 & 511;
    __syncthreads();
    {   // stage A: 64 rows x 32 cols, both planes
      int m = tid >> 2, ch = tid & 3;
      int grow = rowbase + m + half; if (grow > 32767) grow = 32767;
      size_t go = ((size_t)grow << 9) + cb + ch * 8;
      *(uint4*)&Ah [m * 40 + ch * 8] = *(const uint4*)(ahi + go);
      *(uint4*)&Al_[m * 40 + ch * 8] = *(const uint4*)(alo + go);
    }
#pragma unroll
    for (int it = 0; it < 2; ++it) {  // stage W: 128 n x 32 k, both planes
      int i = tid + it * 256;
      int n = i >> 2, ch = i & 3;
      size_t go = (size_t)(ncol0 + n) * 1024 + k0 + ch * 8;
      *(uint4*)&Wh[n * 40 + ch * 8] = *(const uint4*)(w1h + go);
      *(uint4*)&Wl[n * 40 + ch * 8] = *(const uint4*)(w1l + go);
    }
    __syncthreads();

    bf16x8 a_h[2], a_l[2];
#pragma unroll
    for (int mi = 0; mi < 2; ++mi) {
      int off = (wm * 32 + mi * 16 + l15) * 40 + quad * 8;
      a_h[mi] = *(const bf16x8*)&Ah [off];
      a_l[mi] = *(const bf16x8*)&Al_[off];
    }
#pragma unroll
    for (int ni = 0; ni < 4; ++ni) {
      int off = (wn * 64 + ni * 16 + l15) * 40 + quad * 8;
      bf16x8 b_h = *(const bf16x8*)&Wh[off];
      bf16x8 b_l = *(const bf16x8*)&Wl[off];
#pragma unroll
      for (int mi = 0; mi < 2; ++mi) {
        acc[mi][ni] = __builtin_amdgcn_mfma_f32_16x16x32_bf16(a_h[mi], b_h, acc[mi][ni], 0, 0, 0);
        acc[mi][ni] = __builtin_amdgcn_mfma_f32_16x16x32_bf16(a_h[mi], b_l, acc[mi][ni], 0, 0, 0);
        acc[mi][ni] = __builtin_amdgcn_mfma_f32_16x16x32_bf16(a_l[mi], b_h, acc[mi][ni], 0, 0, 0);
      }
    }
  }

  // epilogue: relu(acc + b1) . W2, reduce over the wave's 64 n-cols, atomicAdd
#pragma unroll
  for (int mi = 0; mi < 2; ++mi) {
#pragma unroll
    for (int reg = 0; reg < 4; ++reg) {
      float part = 0.f;
#pragma unroll
      for (int ni = 0; ni < 4; ++ni) {
        int n_g = ncol0 + wn * 64 + ni * 16 + l15;
        float h = acc[mi][ni][reg] + b1[n_g];
        h = h > 0.f ? h : 0.f;
        part = fmaf(h, W2[n_g], part);
      }
#pragma unroll
      for (int m = 8; m; m >>= 1) part += __shfl_xor(part, m, 64);
      if (l15 == 0) {
        int srow = mblk * 64 + wm * 32 + mi * 16 + quad * 4 + reg;
        if (srow < NS) atomicAdd(&S[(size_t)b * NN + srow], part);
      }
    }
  }
}

// ---------------------------------------------------------------- kernel 3 (unchanged)
__global__ __launch_bounds__(256) void k_row(const float* __restrict__ S,
                                             const float* __restrict__ mask,
                                             int* __restrict__ assign,
                                             float* __restrict__ weight,
                                             float* __restrict__ total,
                                             int* __restrict__ startn,
                                             int* __restrict__ endn) {
  int b = blockIdx.x, tid = threadIdx.x;
  __shared__ float Ssh[NS];
  __shared__ float Dsh[NS];
  __shared__ float tsh[NN];
  __shared__ float bsh[NN];
  __shared__ float totl[NN];
  __shared__ int   stl[NN];
  __shared__ int   enl[NN];
  __shared__ float red[256];

  for (int n = tid; n < NS; n += 256) Ssh[n] = S[((size_t)b << 10) + n];
  __syncthreads();

  float mn = INFINITY, mx = -INFINITY;
  for (int n = tid; n < NS; n += 256) {
    float v = Ssh[n];
    mn = fminf(mn, v); mx = fmaxf(mx, v);
  }
  red[tid] = mn; __syncthreads();
  for (int s = 128; s; s >>= 1) { if (tid < s) red[tid] = fminf(red[tid], red[tid + s]); __syncthreads(); }
  float Smin = red[0]; __syncthreads();
  red[tid] = mx; __syncthreads();
  for (int s = 128; s; s >>= 1) { if (tid < s) red[tid] = fmaxf(red[tid], red[tid + s]); __syncthreads(); }
  float Smax = red[0]; __syncthreads();

  for (int n = tid; n < NS; n += 256)
    Dsh[n] = 1.0f - (Ssh[n] - Smin) / (Smax - Smin);
  __syncthreads();

  for (int n = tid; n < NN; n += 256) {
    float P;
    if (n >= NS) {
      P = 0.f;
    } else {
      float D = Dsh[n];
      float fo, so;
      if (n == 0)            fo = fmaxf(D - Dsh[1], 0.f);
      else if (n >= NS - 2)  fo = fmaxf(D - Dsh[n - 2], 0.f);
      else                   fo = fminf(fmaxf(D - Dsh[n - 1], 0.f),
                                        fmaxf(D - Dsh[n + 1], 0.f));
      if (n <= 1)            so = fmaxf(D - Dsh[n + 2], 0.f);
      else if (n >= NS - 2)  so = 0.f;
      else                   so = fminf(fmaxf(D - Dsh[n - 2], 0.f),
                                        fmaxf(D - Dsh[n + 2], 0.f));
      P = fminf(fmaxf(fmaxf(fo, so) - 0.05f, 0.f), fo);
    }
    float m = mask[((size_t)b << 10) + n];
    P = P + (m - 1.0f);
    P = P > 0.f ? P : 0.f;
    float bs = tanhf(10.0f * P);
    float bh = tanhf(100000.0f * P);
    tsh[n] = bs + (bh - bs);
  }
  __syncthreads();

  if (tid == 0) {
    float acc = 0.f;
    for (int n = 0; n < NN; n += 8) {
      float t0 = tsh[n + 0], t1 = tsh[n + 1], t2 = tsh[n + 2], t3 = tsh[n + 3];
      float t4 = tsh[n + 4], t5 = tsh[n + 5], t6 = tsh[n + 6], t7 = tsh[n + 7];
      acc += t0; bsh[n + 0] = acc; acc += t1; bsh[n + 1] = acc;
      acc += t2; bsh[n + 2] = acc; acc += t3; bsh[n + 3] = acc;
      acc += t4; bsh[n + 4] = acc; acc += t5; bsh[n + 5] = acc;
      acc += t6; bsh[n + 6] = acc; acc += t7; bsh[n + 7] = acc;
    }
  }
  __syncthreads();

  float add1 = (bsh[0] == 0.0f) ? 1.0f : 0.0f;
  int   num  = (int)(bsh[NN - 1] + add1) + 1;

  for (int mi = tid; mi < NN; mi += 256) { totl[mi] = 0.f; stl[mi] = 1 << 30; enl[mi] = -1; }
  __syncthreads();

  for (int n = tid; n < NN; n += 256) {
    float bv = bsh[n] + add1;
    float kf = rintf(bv);
    int   k  = (int)kf;
    int   a  = -1; float w = 0.f;
    if (k >= 1 && k <= num && k <= NN) {
      float v = fabsf(kf - bv);
      w = 1.0f - tanhf(100000.0f * v);
      if (w > 0.f) {
        a = k - 1;
        atomicAdd(&totl[a], w);
        atomicMin(&stl[a], n);
        atomicMax(&enl[a], n);
      } else {
        a = -1; w = 0.f;
      }
    }
    assign[((size_t)b << 10) + n] = a;
    weight[((size_t)b << 10) + n] = w;
  }
  __syncthreads();
  for (int mi = tid; mi < NN; mi += 256) {
    total [((size_t)b << 10) + mi] = totl[mi];
    startn[((size_t)b << 10) + mi] = stl[mi];
    endn  [((size_t)b << 10) + mi] = enl[mi];
  }
}

// ---------------------------------------------------------------- kernel 4 (unchanged)
// writes fp32 wrep into d_out (overwrites the A hi/lo planes, which are dead)
__global__ __launch_bounds__(64) void k_pool(const float* __restrict__ seg,
                                             const int* __restrict__ assign,
                                             const float* __restrict__ weight,
                                             const float* __restrict__ total,
                                             const int* __restrict__ startn,
                                             const int* __restrict__ endn,
                                             float* __restrict__ wrep) {
  int bm = blockIdx.x;
  int b  = bm >> 10, m = bm & 1023;
  int lane = threadIdx.x;
  float acc[8] = {0.f, 0.f, 0.f, 0.f, 0.f, 0.f, 0.f, 0.f};
  float tm = total[bm];
  if (tm > 0.f) {
    int s = startn[bm], e = endn[bm];
    for (int n = s; n <= e; ++n) {
      if (assign[((size_t)b << 10) + n] != m) continue;
      float coef = weight[((size_t)b << 10) + n] / tm;
      const float4* p = (const float4*)(seg + (((size_t)b << 10) + n) * HH + lane * 8);
      float4 x = p[0], y = p[1];
      acc[0] = fmaf(coef, x.x, acc[0]); acc[1] = fmaf(coef, x.y, acc[1]);
      acc[2] = fmaf(coef, x.z, acc[2]); acc[3] = fmaf(coef, x.w, acc[3]);
      acc[4] = fmaf(coef, y.x, acc[4]); acc[5] = fmaf(coef, y.y, acc[5]);
      acc[6] = fmaf(coef, y.z, acc[6]); acc[7] = fmaf(coef, y.w, acc[7]);
    }
  }
  float4* dst = (float4*)(wrep + (size_t)bm * HH + lane * 8);
  dst[0] = make_float4(acc[0], acc[1], acc[2], acc[3]);
  dst[1] = make_float4(acc[4], acc[5], acc[6], acc[7]);
}

// ---------------------------------------------------------------- out MLP (MFMA bf16)
// out = (relu(wrep @ We1 + be1) @ We2 + be2) * (wrep != 0), in-place on d_out.
// block: 32 rows x full 512 cols; 4 waves, each 32m x 128n strip. 1-pass bf16.
__global__ __launch_bounds__(256) void k_out(const u16* __restrict__ we1t,
                                             const u16* __restrict__ we2t,
                                             const float* __restrict__ be1,
                                             const float* __restrict__ be2,
                                             float* __restrict__ io) {
  __shared__ u16 Hid[32 * 520];   // hidden bf16 [m][k] stride 520
  __shared__ u16 Wst[512 * 40];   // W chunk [n][k] stride 40
  __shared__ u16 Ast[32 * 40];    // A chunk [m][k] stride 40

  int tid = threadIdx.x;
  int wave = tid >> 6, lane = tid & 63, quad = lane >> 4, l15 = lane & 15;
  int rowbase = blockIdx.x * 32;

  f32x4 acc[2][8];
#pragma unroll
  for (int mi = 0; mi < 2; ++mi)
#pragma unroll
    for (int ni = 0; ni < 8; ++ni) acc[mi][ni] = (f32x4){0.f, 0.f, 0.f, 0.f};

  // ---- phase 1: hidden = relu(wrep @ We1 + be1)
  for (int ks = 0; ks < 16; ++ks) {
    int k0 = ks * 32;
    __syncthreads();
    {   // stage A: 32 rows x 32 cols fp32 -> bf16
      int m = tid >> 3, ch = tid & 7;
      float4 v = *(const float4*)(io + (size_t)(rowbase + m) * HH + k0 + ch * 4);
      u32 p0 = f2bf(v.x) | ((u32)f2bf(v.y) << 16);
      u32 p1 = f2bf(v.z) | ((u32)f2bf(v.w) << 16);
      *(uint2*)&Ast[m * 40 + ch * 4] = make_uint2(p0, p1);
    }
#pragma unroll
    for (int it = 0; it < 8; ++it) {  // stage W: 512 n x 32 k
      int i = tid + it * 256;
      int n = i >> 2, ch = i & 3;
      *(uint4*)&Wst[n * 40 + ch * 8] = *(const uint4*)(we1t + (size_t)n * HH + k0 + ch * 8);
    }
    __syncthreads();

    bf16x8 a[2];
#pragma unroll
    for (int mi = 0; mi < 2; ++mi)
      a[mi] = *(const bf16x8*)&Ast[(mi * 16 + l15) * 40 + quad * 8];
#pragma unroll
    for (int ni = 0; ni < 8; ++ni) {
      bf16x8 bfr = *(const bf16x8*)&Wst[(wave * 128 + ni * 16 + l15) * 40 + quad * 8];
#pragma unroll
      for (int mi = 0; mi < 2; ++mi)
        acc[mi][ni] = __builtin_amdgcn_mfma_f32_16x16x32_bf16(a[mi], bfr, acc[mi][ni], 0, 0, 0);
    }
  }
  // hidden -> LDS (bf16), each wave writes its own 128-col strip
#pragma unroll
  for (int mi = 0; mi < 2; ++mi)
#pragma unroll
    for (int ni = 0; ni < 8; ++ni)
#pragma unroll
      for (int reg = 0; reg < 4; ++reg) {
        int n_g = wave * 128 + ni * 16 + l15;
        float h = acc[mi][ni][reg] + be1[n_g];
        h = h > 0.f ? h : 0.f;
        Hid[(mi * 16 + quad * 4 + reg) * 520 + n_g] = f2bf(h);
      }
  __syncthreads();

#pragma unroll
  for (int mi = 0; mi < 2; ++mi)
#pragma unroll
    for (int ni = 0; ni < 8; ++ni) acc[mi][ni] = (f32x4){0.f, 0.f, 0.f, 0.f};

  // ---- phase 2: out = hidden @ We2 + be2
  for (int ks = 0; ks < 16; ++ks) {
    int k0 = ks * 32;
    __syncthreads();
#pragma unroll
    for (int it = 0; it < 8; ++it) {
      int i = tid + it * 256;
      int n = i >> 2, ch = i & 3;
      *(uint4*)&Wst[n * 40 + ch * 8] = *(const uint4*)(we2t + (size_t)n * HH + k0 + ch * 8);
    }
    __syncthreads();

    bf16x8 a[2];
#pragma unroll
    for (int mi = 0; mi < 2; ++mi)
      a[mi] = *(const bf16x8*)&Hid[(mi * 16 + l15) * 520 + k0 + quad * 8];
#pragma unroll
    for (int ni = 0; ni < 8; ++ni) {
      bf16x8 bfr = *(const bf16x8*)&Wst[(wave * 128 + ni * 16 + l15) * 40 + quad * 8];
#pragma unroll
      for (int mi = 0; mi < 2; ++mi)
        acc[mi][ni] = __builtin_amdgcn_mfma_f32_16x16x32_bf16(a[mi], bfr, acc[mi][ni], 0, 0, 0);
    }
  }

  // epilogue: bias + (wrep == 0) mask, in-place f32 store (element-exclusive)
#pragma unroll
  for (int mi = 0; mi < 2; ++mi)
#pragma unroll
    for (int ni = 0; ni < 8; ++ni)
#pragma unroll
      for (int reg = 0; reg < 4; ++reg) {
        int n_g = wave * 128 + ni * 16 + l15;
        size_t row = (size_t)(rowbase + mi * 16 + quad * 4 + reg);
        float o = acc[mi][ni][reg] + be2[n_g];
        float wr = io[row * HH + n_g];
        io[row * HH + n_g] = (wr == 0.f) ? 0.f : o;
      }
}

// ---------------------------------------------------------------- diag (hostcode only)
__global__ void k_diag(float* __restrict__ out, int hostcode) {
  if (hostcode != 0) out[0] = (float)hostcode;
}

// ---------------------------------------------------------------- launch
extern "C" void kernel_launch(void* const* d_in, const int* in_sizes, int n_in,
                              void* d_out, int out_size, void* d_ws, size_t ws_size,
                              hipStream_t stream) {
  const float* seg  = (const float*)d_in[0];
  const float* mask = (const float*)d_in[1];
  const float* W1   = (const float*)d_in[2];
  const float* b1   = (const float*)d_in[3];
  const float* W2   = (const float*)d_in[4];
  const float* We1  = (const float*)d_in[5];
  const float* be1  = (const float*)d_in[6];
  const float* We2  = (const float*)d_in[7];
  const float* be2  = (const float*)d_in[8];

  const size_t NROW = (size_t)BB * NN;            // 32768
  float* ws = (float*)d_ws;
  float* S      = ws;
  int*   assign = (int*)(S + NROW);
  float* weight = (float*)(assign + NROW);
  float* total  = weight + NROW;
  int*   startn = (int*)(total + NROW);
  int*   endn   = startn + NROW;
  u16*   w1h    = (u16*)(endn + NROW);            // 512x1024
  u16*   w1l    = w1h + (size_t)512 * 1024;
  u16*   we1t   = w1l + (size_t)512 * 1024;       // 512x512
  u16*   we2t   = we1t + (size_t)512 * 512;       // end ~3.9 MB

  float* out = (float*)d_out;
  u16*   ahi = (u16*)d_out;                       // A hi plane (33.5 MB)
  u16*   alo = ahi + (size_t)NROW * HH;           // A lo plane (33.5 MB)

  int hostcode = 0;
  if (ws_size < (size_t)6 * NROW * 4 + (size_t)512 * 1024 * 4 + (size_t)512 * 512 * 4)
    hostcode += 32768;
  if (out_size != 16777216) hostcode += 8192;

  k_prep_a<<<dim3(BB * NN), dim3(64), 0, stream>>>(seg, ahi, alo);
  k_prep_w<<<dim3(512), dim3(256), 0, stream>>>(W1, We1, We2, w1h, w1l, we1t, we2t, S);
  k_sgemm <<<dim3(4, 16, BB), dim3(256), 0, stream>>>(ahi, alo, w1h, w1l, b1, W2, S);
  k_row   <<<dim3(BB), dim3(256), 0, stream>>>(S, mask, assign, weight, total, startn, endn);
  k_pool  <<<dim3(BB * NN), dim3(64), 0, stream>>>(seg, assign, weight, total, startn, endn, out);
  k_out   <<<dim3(NROW / 32), dim3(256), 0, stream>>>(we1t, we2t, be1, be2, out);
  k_diag  <<<dim3(1), dim3(1), 0, stream>>>(out, hostcode);
}

// Round 6
// 387.646 us; speedup vs baseline: 8.6977x; 1.0368x over previous
//
#include <hip/hip_runtime.h>

#define BB 32
#define NN 1024
#define HH 512
#define NS 1023   // S length per row

typedef unsigned short u16;
typedef unsigned int   u32;
typedef __attribute__((ext_vector_type(8))) short bf16x8;
typedef __attribute__((ext_vector_type(4))) float f32x4;

__device__ __forceinline__ float bf2f(u16 h) {
  union { u32 u; float f; } c; c.u = ((u32)h) << 16; return c.f;
}
__device__ __forceinline__ u16 f2bf(float f) {
  union { float f; u32 u; } c; c.f = f;
  u32 u = c.u;
  return (u16)((u + 0x7fffu + ((u >> 16) & 1u)) >> 16);
}
// split x = hi + lo (each bf16); residual ~2^-18 relative
__device__ __forceinline__ void split_bf(float x, u16& hi, u16& lo) {
  hi = f2bf(x);
  lo = f2bf(x - bf2f(hi));
}

// ---------------------------------------------------------------- prep A
// normalize seg rows, split to bf16 hi/lo planes stored in d_out
__global__ __launch_bounds__(64) void k_prep_a(const float* __restrict__ seg,
                                               u16* __restrict__ ahi,
                                               u16* __restrict__ alo) {
  int row = blockIdx.x, lane = threadIdx.x;
  const float4* p = (const float4*)(seg + ((size_t)row << 9) + lane * 8);
  float4 a = p[0], b = p[1];
  float v[8] = {a.x, a.y, a.z, a.w, b.x, b.y, b.z, b.w};
  float s = 0.f;
#pragma unroll
  for (int i = 0; i < 8; ++i) s += v[i] * v[i];
#pragma unroll
  for (int m = 32; m; m >>= 1) s += __shfl_xor(s, m, 64);
  float nrm = sqrtf(s);
  u16 h[8], l[8];
#pragma unroll
  for (int i = 0; i < 8; ++i) split_bf(v[i] / nrm, h[i], l[i]);
  size_t off = ((size_t)row << 9) + lane * 8;
  *(uint4*)(ahi + off) = make_uint4(h[0] | (h[1] << 16), h[2] | (h[3] << 16),
                                    h[4] | (h[5] << 16), h[6] | (h[7] << 16));
  *(uint4*)(alo + off) = make_uint4(l[0] | (l[1] << 16), l[2] | (l[3] << 16),
                                    l[4] | (l[5] << 16), l[6] | (l[7] << 16));
}

// ---------------------------------------------------------------- transpose-split
// src (K x N, row-major) -> dh[n][k] (+ dl[n][k] if dl != nullptr), bf16.
// 64x64 tiles via LDS, coalesced both sides. grid (N/64, K/64), 256 thr.
__global__ __launch_bounds__(256) void k_tr(const float* __restrict__ src,
                                            u16* __restrict__ dh,
                                            u16* __restrict__ dl,
                                            int K, int N) {
  __shared__ u16 Th[64 * 66], Tl[64 * 66];
  int nb = blockIdx.x * 64, kb = blockIdx.y * 64;
  int tid = threadIdx.x;
#pragma unroll
  for (int i = 0; i < 16; ++i) {
    int e = tid + i * 256;
    int r = e >> 6, c = e & 63;                 // r = k index, c = n index
    float v = src[(size_t)(kb + r) * N + nb + c];
    u16 hi, lo; split_bf(v, hi, lo);
    Th[c * 66 + r] = hi;
    Tl[c * 66 + r] = lo;
  }
  __syncthreads();
#pragma unroll
  for (int i = 0; i < 16; ++i) {
    int e = tid + i * 256;
    int n = e >> 6, k = e & 63;
    dh[(size_t)(nb + n) * K + kb + k] = Th[n * 66 + k];
    if (dl) dl[(size_t)(nb + n) * K + kb + k] = Tl[n * 66 + k];
  }
}

// ---------------------------------------------------------------- S-GEMM (MFMA)
// hidden = relu(cat(A[n],A[n+1]) @ W1 + b1); Spart[nblk] = hidden_strip . W2
// block tile: 64 S-rows x 256 hidden cols; 4 waves, wave tile 64m x 64n.
// 3-pass split bf16. grid (2 nblk, 16 mblk, 32 b), 256 thr.
__global__ __launch_bounds__(256) void k_sgemm(const u16* __restrict__ ahi,
                                               const u16* __restrict__ alo,
                                               const u16* __restrict__ w1h,
                                               const u16* __restrict__ w1l,
                                               const float* __restrict__ b1,
                                               const float* __restrict__ W2,
                                               float* __restrict__ Spart) {
  __shared__ u16 Ah[64 * 40], Al_[64 * 40];   // [m][k] stride 40 (16B-aligned rows)
  __shared__ u16 Wh[256 * 40], Wl[256 * 40];  // [n][k] stride 40
  __shared__ float red[4][64];

  int tid = threadIdx.x;
  int wave = tid >> 6, lane = tid & 63, quad = lane >> 4, l15 = lane & 15;
  int b = blockIdx.z, mblk = blockIdx.y, nblk = blockIdx.x;
  int rowbase = b * NN + mblk * 64;
  int ncol0 = nblk * 256;

  f32x4 acc[4][4];
#pragma unroll
  for (int mi = 0; mi < 4; ++mi)
#pragma unroll
    for (int ni = 0; ni < 4; ++ni) acc[mi][ni] = (f32x4){0.f, 0.f, 0.f, 0.f};

  for (int ks = 0; ks < 32; ++ks) {
    int k0 = ks * 32, half = k0 >> 9, cb = k0 & 511;
    __syncthreads();
#pragma unroll
    for (int it = 0; it < 2; ++it) {   // stage A: 64m x 32k, hi+lo
      int i = tid + it * 256;
      int m = i >> 3, plane = (i >> 2) & 1, ch = i & 3;
      int grow = rowbase + m + half; if (grow > 32767) grow = 32767;
      size_t go = ((size_t)grow << 9) + cb + ch * 8;
      if (plane) *(uint4*)&Al_[m * 40 + ch * 8] = *(const uint4*)(alo + go);
      else       *(uint4*)&Ah [m * 40 + ch * 8] = *(const uint4*)(ahi + go);
    }
#pragma unroll
    for (int it = 0; it < 8; ++it) {   // stage W: 256n x 32k, hi+lo
      int i = tid + it * 256;
      int n = i >> 3, plane = (i >> 2) & 1, ch = i & 3;
      size_t go = (size_t)(ncol0 + n) * 1024 + k0 + ch * 8;
      if (plane) *(uint4*)&Wl[n * 40 + ch * 8] = *(const uint4*)(w1l + go);
      else       *(uint4*)&Wh[n * 40 + ch * 8] = *(const uint4*)(w1h + go);
    }
    __syncthreads();

    bf16x8 a_h[4], a_l[4];
#pragma unroll
    for (int mi = 0; mi < 4; ++mi) {
      int off = (mi * 16 + l15) * 40 + quad * 8;
      a_h[mi] = *(const bf16x8*)&Ah [off];
      a_l[mi] = *(const bf16x8*)&Al_[off];
    }
#pragma unroll
    for (int ni = 0; ni < 4; ++ni) {
      int off = (wave * 64 + ni * 16 + l15) * 40 + quad * 8;
      bf16x8 b_h = *(const bf16x8*)&Wh[off];
      bf16x8 b_l = *(const bf16x8*)&Wl[off];
#pragma unroll
      for (int mi = 0; mi < 4; ++mi) {
        acc[mi][ni] = __builtin_amdgcn_mfma_f32_16x16x32_bf16(a_h[mi], b_h, acc[mi][ni], 0, 0, 0);
        acc[mi][ni] = __builtin_amdgcn_mfma_f32_16x16x32_bf16(a_h[mi], b_l, acc[mi][ni], 0, 0, 0);
        acc[mi][ni] = __builtin_amdgcn_mfma_f32_16x16x32_bf16(a_l[mi], b_h, acc[mi][ni], 0, 0, 0);
      }
    }
  }

  // epilogue: relu(acc + b1) . W2 over this wave's 64 cols; reduce, no atomics
#pragma unroll
  for (int mi = 0; mi < 4; ++mi) {
#pragma unroll
    for (int reg = 0; reg < 4; ++reg) {
      float part = 0.f;
#pragma unroll
      for (int ni = 0; ni < 4; ++ni) {
        int n_g = ncol0 + wave * 64 + ni * 16 + l15;
        float h = acc[mi][ni][reg] + b1[n_g];
        h = h > 0.f ? h : 0.f;
        part = fmaf(h, W2[n_g], part);
      }
#pragma unroll
      for (int m = 8; m; m >>= 1) part += __shfl_xor(part, m, 64);
      if (l15 == 0) red[wave][mi * 16 + quad * 4 + reg] = part;
    }
  }
  __syncthreads();
  if (tid < 64) {
    float s = red[0][tid] + red[1][tid] + red[2][tid] + red[3][tid];
    int srow = mblk * 64 + tid;
    if (srow < NS)
      Spart[((size_t)nblk * BB + b) * NN + srow] = s;
  }
}

// ---------------------------------------------------------------- kernel 3
__global__ __launch_bounds__(256) void k_row(const float* __restrict__ S0,
                                             const float* __restrict__ S1,
                                             const float* __restrict__ mask,
                                             int* __restrict__ assign,
                                             float* __restrict__ weight,
                                             float* __restrict__ total,
                                             int* __restrict__ startn,
                                             int* __restrict__ endn) {
  int b = blockIdx.x, tid = threadIdx.x;
  __shared__ float Ssh[NS];
  __shared__ float Dsh[NS];
  __shared__ float tsh[NN];
  __shared__ float bsh[NN];
  __shared__ float totl[NN];
  __shared__ int   stl[NN];
  __shared__ int   enl[NN];
  __shared__ float red[256];

  for (int n = tid; n < NS; n += 256)
    Ssh[n] = S0[((size_t)b << 10) + n] + S1[((size_t)b << 10) + n];
  __syncthreads();

  float mn = INFINITY, mx = -INFINITY;
  for (int n = tid; n < NS; n += 256) {
    float v = Ssh[n];
    mn = fminf(mn, v); mx = fmaxf(mx, v);
  }
  red[tid] = mn; __syncthreads();
  for (int s = 128; s; s >>= 1) { if (tid < s) red[tid] = fminf(red[tid], red[tid + s]); __syncthreads(); }
  float Smin = red[0]; __syncthreads();
  red[tid] = mx; __syncthreads();
  for (int s = 128; s; s >>= 1) { if (tid < s) red[tid] = fmaxf(red[tid], red[tid + s]); __syncthreads(); }
  float Smax = red[0]; __syncthreads();

  for (int n = tid; n < NS; n += 256)
    Dsh[n] = 1.0f - (Ssh[n] - Smin) / (Smax - Smin);
  __syncthreads();

  for (int n = tid; n < NN; n += 256) {
    float P;
    if (n >= NS) {
      P = 0.f;
    } else {
      float D = Dsh[n];
      float fo, so;
      if (n == 0)            fo = fmaxf(D - Dsh[1], 0.f);
      else if (n >= NS - 2)  fo = fmaxf(D - Dsh[n - 2], 0.f);
      else                   fo = fminf(fmaxf(D - Dsh[n - 1], 0.f),
                                        fmaxf(D - Dsh[n + 1], 0.f));
      if (n <= 1)            so = fmaxf(D - Dsh[n + 2], 0.f);
      else if (n >= NS - 2)  so = 0.f;
      else                   so = fminf(fmaxf(D - Dsh[n - 2], 0.f),
                                        fmaxf(D - Dsh[n + 2], 0.f));
      P = fminf(fmaxf(fmaxf(fo, so) - 0.05f, 0.f), fo);
    }
    float m = mask[((size_t)b << 10) + n];
    P = P + (m - 1.0f);
    P = P > 0.f ? P : 0.f;
    float bs = tanhf(10.0f * P);
    float bh = tanhf(100000.0f * P);
    tsh[n] = bs + (bh - bs);
  }
  __syncthreads();

  if (tid == 0) {
    float acc = 0.f;
    for (int n = 0; n < NN; n += 8) {
      float t0 = tsh[n + 0], t1 = tsh[n + 1], t2 = tsh[n + 2], t3 = tsh[n + 3];
      float t4 = tsh[n + 4], t5 = tsh[n + 5], t6 = tsh[n + 6], t7 = tsh[n + 7];
      acc += t0; bsh[n + 0] = acc; acc += t1; bsh[n + 1] = acc;
      acc += t2; bsh[n + 2] = acc; acc += t3; bsh[n + 3] = acc;
      acc += t4; bsh[n + 4] = acc; acc += t5; bsh[n + 5] = acc;
      acc += t6; bsh[n + 6] = acc; acc += t7; bsh[n + 7] = acc;
    }
  }
  __syncthreads();

  float add1 = (bsh[0] == 0.0f) ? 1.0f : 0.0f;
  int   num  = (int)(bsh[NN - 1] + add1) + 1;

  for (int mi = tid; mi < NN; mi += 256) { totl[mi] = 0.f; stl[mi] = 1 << 30; enl[mi] = -1; }
  __syncthreads();

  for (int n = tid; n < NN; n += 256) {
    float bv = bsh[n] + add1;
    float kf = rintf(bv);
    int   k  = (int)kf;
    int   a  = -1; float w = 0.f;
    if (k >= 1 && k <= num && k <= NN) {
      float v = fabsf(kf - bv);
      w = 1.0f - tanhf(100000.0f * v);
      if (w > 0.f) {
        a = k - 1;
        atomicAdd(&totl[a], w);
        atomicMin(&stl[a], n);
        atomicMax(&enl[a], n);
      } else {
        a = -1; w = 0.f;
      }
    }
    assign[((size_t)b << 10) + n] = a;
    weight[((size_t)b << 10) + n] = w;
  }
  __syncthreads();
  for (int mi = tid; mi < NN; mi += 256) {
    total [((size_t)b << 10) + mi] = totl[mi];
    startn[((size_t)b << 10) + mi] = stl[mi];
    endn  [((size_t)b << 10) + mi] = enl[mi];
  }
}

// ---------------------------------------------------------------- kernel 4
// writes fp32 wrep into d_out (overwrites dead A hi/lo planes)
__global__ __launch_bounds__(64) void k_pool(const float* __restrict__ seg,
                                             const int* __restrict__ assign,
                                             const float* __restrict__ weight,
                                             const float* __restrict__ total,
                                             const int* __restrict__ startn,
                                             const int* __restrict__ endn,
                                             float* __restrict__ wrep) {
  int bm = blockIdx.x;
  int b  = bm >> 10, m = bm & 1023;
  int lane = threadIdx.x;
  float acc[8] = {0.f, 0.f, 0.f, 0.f, 0.f, 0.f, 0.f, 0.f};
  float tm = total[bm];
  if (tm > 0.f) {
    int s = startn[bm], e = endn[bm];
    for (int n = s; n <= e; ++n) {
      if (assign[((size_t)b << 10) + n] != m) continue;
      float coef = weight[((size_t)b << 10) + n] / tm;
      const float4* p = (const float4*)(seg + (((size_t)b << 10) + n) * HH + lane * 8);
      float4 x = p[0], y = p[1];
      acc[0] = fmaf(coef, x.x, acc[0]); acc[1] = fmaf(coef, x.y, acc[1]);
      acc[2] = fmaf(coef, x.z, acc[2]); acc[3] = fmaf(coef, x.w, acc[3]);
      acc[4] = fmaf(coef, y.x, acc[4]); acc[5] = fmaf(coef, y.y, acc[5]);
      acc[6] = fmaf(coef, y.z, acc[6]); acc[7] = fmaf(coef, y.w, acc[7]);
    }
  }
  float4* dst = (float4*)(wrep + (size_t)bm * HH + lane * 8);
  dst[0] = make_float4(acc[0], acc[1], acc[2], acc[3]);
  dst[1] = make_float4(acc[4], acc[5], acc[6], acc[7]);
}

// ---------------------------------------------------------------- out MLP (MFMA bf16)
// out = (relu(wrep @ We1 + be1) @ We2 + be2) * (wrep != 0), in-place on d_out.
// block: 64 rows x 512 cols; 8 waves as 2m x 4n, wave tile 32m x 128n.
__global__ __launch_bounds__(512) void k_out(const u16* __restrict__ we1t,
                                             const u16* __restrict__ we2t,
                                             const float* __restrict__ be1,
                                             const float* __restrict__ be2,
                                             float* __restrict__ io) {
  __shared__ u16 Hid[64 * 520];   // hidden bf16 [m][k] stride 520
  __shared__ u16 Wst[512 * 40];   // W chunk [n][k] stride 40
  __shared__ u16 Ast[64 * 40];    // A chunk [m][k] stride 40

  int tid = threadIdx.x;
  int wave = tid >> 6, lane = tid & 63, quad = lane >> 4, l15 = lane & 15;
  int wm = wave >> 2, wn = wave & 3;
  int rowbase = blockIdx.x * 64;

  f32x4 acc[2][8];
#pragma unroll
  for (int mi = 0; mi < 2; ++mi)
#pragma unroll
    for (int ni = 0; ni < 8; ++ni) acc[mi][ni] = (f32x4){0.f, 0.f, 0.f, 0.f};

  // ---- phase 1: hidden = relu(wrep @ We1 + be1)
  for (int ks = 0; ks < 16; ++ks) {
    int k0 = ks * 32;
    __syncthreads();
    {   // stage A: 64 rows x 32 cols fp32 -> bf16
      int m = tid >> 3, ch = tid & 7;
      float4 v = *(const float4*)(io + (size_t)(rowbase + m) * HH + k0 + ch * 4);
      u32 p0 = f2bf(v.x) | ((u32)f2bf(v.y) << 16);
      u32 p1 = f2bf(v.z) | ((u32)f2bf(v.w) << 16);
      *(uint2*)&Ast[m * 40 + ch * 4] = make_uint2(p0, p1);
    }
#pragma unroll
    for (int it = 0; it < 4; ++it) {  // stage W: 512n x 32k
      int i = tid + it * 512;
      int n = i >> 2, ch = i & 3;
      *(uint4*)&Wst[n * 40 + ch * 8] = *(const uint4*)(we1t + (size_t)n * HH + k0 + ch * 8);
    }
    __syncthreads();

    bf16x8 a[2];
#pragma unroll
    for (int mi = 0; mi < 2; ++mi)
      a[mi] = *(const bf16x8*)&Ast[(wm * 32 + mi * 16 + l15) * 40 + quad * 8];
#pragma unroll
    for (int ni = 0; ni < 8; ++ni) {
      bf16x8 bfr = *(const bf16x8*)&Wst[(wn * 128 + ni * 16 + l15) * 40 + quad * 8];
#pragma unroll
      for (int mi = 0; mi < 2; ++mi)
        acc[mi][ni] = __builtin_amdgcn_mfma_f32_16x16x32_bf16(a[mi], bfr, acc[mi][ni], 0, 0, 0);
    }
  }
  // hidden -> LDS (bf16)
#pragma unroll
  for (int mi = 0; mi < 2; ++mi)
#pragma unroll
    for (int ni = 0; ni < 8; ++ni)
#pragma unroll
      for (int reg = 0; reg < 4; ++reg) {
        int n_g = wn * 128 + ni * 16 + l15;
        float h = acc[mi][ni][reg] + be1[n_g];
        h = h > 0.f ? h : 0.f;
        Hid[(wm * 32 + mi * 16 + quad * 4 + reg) * 520 + n_g] = f2bf(h);
      }

#pragma unroll
  for (int mi = 0; mi < 2; ++mi)
#pragma unroll
    for (int ni = 0; ni < 8; ++ni) acc[mi][ni] = (f32x4){0.f, 0.f, 0.f, 0.f};

  // ---- phase 2: out = hidden @ We2 + be2
  for (int ks = 0; ks < 16; ++ks) {
    int k0 = ks * 32;
    __syncthreads();
#pragma unroll
    for (int it = 0; it < 4; ++it) {
      int i = tid + it * 512;
      int n = i >> 2, ch = i & 3;
      *(uint4*)&Wst[n * 40 + ch * 8] = *(const uint4*)(we2t + (size_t)n * HH + k0 + ch * 8);
    }
    __syncthreads();

    bf16x8 a[2];
#pragma unroll
    for (int mi = 0; mi < 2; ++mi)
      a[mi] = *(const bf16x8*)&Hid[(wm * 32 + mi * 16 + l15) * 520 + k0 + quad * 8];
#pragma unroll
    for (int ni = 0; ni < 8; ++ni) {
      bf16x8 bfr = *(const bf16x8*)&Wst[(wn * 128 + ni * 16 + l15) * 40 + quad * 8];
#pragma unroll
      for (int mi = 0; mi < 2; ++mi)
        acc[mi][ni] = __builtin_amdgcn_mfma_f32_16x16x32_bf16(a[mi], bfr, acc[mi][ni], 0, 0, 0);
    }
  }

  // epilogue: bias + (wrep == 0) mask, in-place f32 store (element-exclusive)
#pragma unroll
  for (int mi = 0; mi < 2; ++mi)
#pragma unroll
    for (int ni = 0; ni < 8; ++ni)
#pragma unroll
      for (int reg = 0; reg < 4; ++reg) {
        int n_g = wn * 128 + ni * 16 + l15;
        size_t row = (size_t)(rowbase + wm * 32 + mi * 16 + quad * 4 + reg);
        float o = acc[mi][ni][reg] + be2[n_g];
        float wr = io[row * HH + n_g];
        io[row * HH + n_g] = (wr == 0.f) ? 0.f : o;
      }
}

// ---------------------------------------------------------------- diag (hostcode only)
__global__ void k_diag(float* __restrict__ out, int hostcode) {
  if (hostcode != 0) out[0] = (float)hostcode;
}

// ---------------------------------------------------------------- launch
extern "C" void kernel_launch(void* const* d_in, const int* in_sizes, int n_in,
                              void* d_out, int out_size, void* d_ws, size_t ws_size,
                              hipStream_t stream) {
  const float* seg  = (const float*)d_in[0];
  const float* mask = (const float*)d_in[1];
  const float* W1   = (const float*)d_in[2];
  const float* b1   = (const float*)d_in[3];
  const float* W2   = (const float*)d_in[4];
  const float* We1  = (const float*)d_in[5];
  const float* be1  = (const float*)d_in[6];
  const float* We2  = (const float*)d_in[7];
  const float* be2  = (const float*)d_in[8];

  const size_t NROW = (size_t)BB * NN;            // 32768
  float* ws = (float*)d_ws;
  float* S0     = ws;                             // partial S, nblk=0
  float* S1     = S0 + NROW;                      // partial S, nblk=1
  int*   assign = (int*)(S1 + NROW);
  float* weight = (float*)(assign + NROW);
  float* total  = weight + NROW;
  int*   startn = (int*)(total + NROW);
  int*   endn   = startn + NROW;
  u16*   w1h    = (u16*)(endn + NROW);            // [n=512][k=1024]
  u16*   w1l    = w1h + (size_t)512 * 1024;
  u16*   we1t   = w1l + (size_t)512 * 1024;       // [n=512][k=512]
  u16*   we2t   = we1t + (size_t)512 * 512;       // end ~3.9 MB

  float* out = (float*)d_out;
  u16*   ahi = (u16*)d_out;                       // A hi plane (33.5 MB)
  u16*   alo = ahi + (size_t)NROW * HH;           // A lo plane (33.5 MB)

  int hostcode = 0;
  if (ws_size < (size_t)7 * NROW * 4 + (size_t)3 * 1024 * 1024) hostcode += 32768;
  if (out_size != 16777216) hostcode += 8192;

  k_prep_a<<<dim3(BB * NN), dim3(64), 0, stream>>>(seg, ahi, alo);
  k_tr    <<<dim3(8, 16), dim3(256), 0, stream>>>(W1, w1h, w1l, 1024, 512);
  k_tr    <<<dim3(8, 8),  dim3(256), 0, stream>>>(We1, we1t, (u16*)nullptr, 512, 512);
  k_tr    <<<dim3(8, 8),  dim3(256), 0, stream>>>(We2, we2t, (u16*)nullptr, 512, 512);
  k_sgemm <<<dim3(2, 16, BB), dim3(256), 0, stream>>>(ahi, alo, w1h, w1l, b1, W2, S0);
  k_row   <<<dim3(BB), dim3(256), 0, stream>>>(S0, S1, mask, assign, weight, total, startn, endn);
  k_pool  <<<dim3(BB * NN), dim3(64), 0, stream>>>(seg, assign, weight, total, startn, endn, out);
  k_out   <<<dim3(NROW / 64), dim3(512), 0, stream>>>(we1t, we2t, be1, be2, out);
  k_diag  <<<dim3(1), dim3(1), 0, stream>>>(out, hostcode);
}